// Round 8
// baseline (202.218 us; speedup 1.0000x reference)
//
#include <hip/hip_runtime.h>
#include <math.h>

// LearnableVisitEncoder — 3-kernel pipeline, all fp32:
//   A vocab_fused : emb[20000,128] -> H2 = silu(silu(emb@W1+b1)@W2+b2) (stored)
//                   L[r] = tanh(H2@Wa1+ba1) . wa2 + ba2                (stored)
//   B pool_kernel : per visit masked softmax over L[ids], HP = sum a_c H2[id_c]
//   C rho_fused   : out = silu(HP@Wr1+br1)@Wr2 + br2
//
// GEMM: wave-column-split + K-SPLIT, 512-thread blocks (8 waves).
// Waves 0-3: k 0..63; waves 4-7: k 64..127 of the SAME 32x128 tile.
// Upper half writes fp32 partials to LDS sC; lower half combines+epilogue.
// This doubles waves/SIMD (2.44 -> 4.88) at constant per-thread tile shape.
// Journal constraints (hard-won):
//   - r4: runtime-indexed local arrays -> scratch spill (2.6 GB HBM). NEVER.
//   - r5: full unroll of k-loop -> scratch spill (3.4 GB HBM). NEVER.
//   - r6: smaller per-wave tiles (MT=16) regressed: keep acc[4][4]/unroll-4.
//   - r7: deeper per-wave pipelining: VALUBusy 31->42% but dur flat. Wave
//     count, not per-wave depth, is the lever (this round tests exactly that).

#define DIM 128
#define MT 32
#define KH 64    // k-half per wave group
#define LDP 132  // LDS row stride (528 B), 16B-aligned

__device__ __forceinline__ float silu_f(float v) {
  return v / (1.0f + expf(-v));
}

// stage 32 x 128 fp32 rows (contiguous global) into LDS tile; 512 threads
__device__ __forceinline__ void stage32(const float* __restrict__ src,
                                        float (*dst)[LDP], int tid) {
  const float4* s = (const float4*)src;
#pragma unroll
  for (int t = 0; t < 2; ++t) {
    int idx = tid + t * 512;          // 0..1023 float4s = 32 rows x 32
    int r = idx >> 5, c4 = idx & 31;
    *(float4*)&dst[r][c4 * 4] = s[idx];
  }
}

#define FMA4R(i, xs, wv)                                                    \
  acc[i][0] = fmaf(xs, wv.x, acc[i][0]);                                    \
  acc[i][1] = fmaf(xs, wv.y, acc[i][1]);                                    \
  acc[i][2] = fmaf(xs, wv.z, acc[i][2]);                                    \
  acc[i][3] = fmaf(xs, wv.w, acc[i][3]);
#define FMAK(comp, wv)                                                      \
  FMA4R(0, x0.comp, wv) FMA4R(1, x1.comp, wv)                               \
  FMA4R(2, x2.comp, wv) FMA4R(3, x3.comp, wv)

// acc[4][4] = sIn[r0..r0+3][kbase..kbase+KH) @ W[kbase..)[4*cg..4*cg+3]
// r3-proven inner loop: partial unroll 4, static indices only
__device__ __forceinline__ void gemm_half(const float (*sIn)[LDP],
                                          const float* __restrict__ Wg,
                                          int cg, int r0, int kbase,
                                          float acc[4][4]) {
#pragma unroll
  for (int i = 0; i < 4; ++i)
#pragma unroll
    for (int j = 0; j < 4; ++j) acc[i][j] = 0.f;
  const float4* Wv = (const float4*)Wg;  // W[k][c]: float4 index k*32 + cg
#pragma unroll 4
  for (int k0 = kbase; k0 < kbase + KH; k0 += 4) {
    float4 x0 = *(const float4*)&sIn[r0 + 0][k0];
    float4 x1 = *(const float4*)&sIn[r0 + 1][k0];
    float4 x2 = *(const float4*)&sIn[r0 + 2][k0];
    float4 x3 = *(const float4*)&sIn[r0 + 3][k0];
    float4 w0 = Wv[(k0 + 0) * 32 + cg];
    float4 w1 = Wv[(k0 + 1) * 32 + cg];
    float4 w2 = Wv[(k0 + 2) * 32 + cg];
    float4 w3 = Wv[(k0 + 3) * 32 + cg];
    FMAK(x, w0)
    FMAK(y, w1)
    FMAK(z, w2)
    FMAK(w, w3)
  }
}

// ---------------- Kernel A: vocab side, fully fused ----------------
__global__ __launch_bounds__(512, 4) void vocab_fused(
    const float* __restrict__ emb, const float* __restrict__ W1,
    const float* __restrict__ b1, const float* __restrict__ W2,
    const float* __restrict__ b2, const float* __restrict__ Wa1,
    const float* __restrict__ ba1, const float* __restrict__ wa2,
    const float* __restrict__ ba2, float* __restrict__ H2,
    float* __restrict__ L) {
  __shared__ float sA[MT][LDP], sB[MT][LDP], sC[MT][LDP];
  __shared__ float sP[4][MT];
  const int tid = threadIdx.x;
  const int wid = tid >> 6, lane = tid & 63;
  const int kw = wid >> 2;              // 0 = k-lo half, 1 = k-hi half
  const int w4 = wid & 3;               // wave within half
  const int cg = w4 * 8 + (lane & 7);   // float4-col index 0..31
  const int c0 = cg * 4;
  const int r0 = (lane >> 3) * 4;       // 8 row-groups x 4 rows
  const int kbase = kw * KH;
  const int m0 = blockIdx.x * MT;

  stage32(emb + (size_t)m0 * DIM, sA, tid);
  __syncthreads();

  float acc[4][4];
  // ---- layer 1: silu(emb@W1+b1) -> sB
  gemm_half(sA, W1, cg, r0, kbase, acc);
  if (kw) {
#pragma unroll
    for (int i = 0; i < 4; ++i)
      *(float4*)&sC[r0 + i][c0] =
          make_float4(acc[i][0], acc[i][1], acc[i][2], acc[i][3]);
  }
  __syncthreads();
  if (!kw) {
    float4 bv = ((const float4*)b1)[cg];
#pragma unroll
    for (int i = 0; i < 4; ++i) {
      float4 pc = *(const float4*)&sC[r0 + i][c0];
      float4 o;
      o.x = silu_f(acc[i][0] + pc.x + bv.x);
      o.y = silu_f(acc[i][1] + pc.y + bv.y);
      o.z = silu_f(acc[i][2] + pc.z + bv.z);
      o.w = silu_f(acc[i][3] + pc.w + bv.w);
      *(float4*)&sB[r0 + i][c0] = o;
    }
  }
  __syncthreads();
  // ---- layer 2: silu(sB@W2+b2) -> sA + global H2
  gemm_half(sB, W2, cg, r0, kbase, acc);
  if (kw) {
#pragma unroll
    for (int i = 0; i < 4; ++i)
      *(float4*)&sC[r0 + i][c0] =
          make_float4(acc[i][0], acc[i][1], acc[i][2], acc[i][3]);
  }
  __syncthreads();
  if (!kw) {
    float4 bv = ((const float4*)b2)[cg];
#pragma unroll
    for (int i = 0; i < 4; ++i) {
      float4 pc = *(const float4*)&sC[r0 + i][c0];
      float4 o;
      o.x = silu_f(acc[i][0] + pc.x + bv.x);
      o.y = silu_f(acc[i][1] + pc.y + bv.y);
      o.z = silu_f(acc[i][2] + pc.z + bv.z);
      o.w = silu_f(acc[i][3] + pc.w + bv.w);
      *(float4*)&sA[r0 + i][c0] = o;
      *(float4*)&H2[(size_t)(m0 + r0 + i) * DIM + c0] = o;
    }
  }
  __syncthreads();
  // ---- layer 3: tanh(sA@Wa1+ba1) . wa2 + ba2 -> L (rowdot fused)
  gemm_half(sA, Wa1, cg, r0, kbase, acc);
  if (kw) {
#pragma unroll
    for (int i = 0; i < 4; ++i)
      *(float4*)&sC[r0 + i][c0] =
          make_float4(acc[i][0], acc[i][1], acc[i][2], acc[i][3]);
  }
  __syncthreads();
  if (!kw) {
    float4 bv = ((const float4*)ba1)[cg];
    float4 wv = ((const float4*)wa2)[cg];
#pragma unroll
    for (int i = 0; i < 4; ++i) {
      float4 pc = *(const float4*)&sC[r0 + i][c0];
      float g0 = tanhf(acc[i][0] + pc.x + bv.x);
      float g1 = tanhf(acc[i][1] + pc.y + bv.y);
      float g2 = tanhf(acc[i][2] + pc.z + bv.z);
      float g3 = tanhf(acc[i][3] + pc.w + bv.w);
      float p = fmaf(g0, wv.x, fmaf(g1, wv.y, fmaf(g2, wv.z, g3 * wv.w)));
#pragma unroll
      for (int m = 1; m <= 4; m <<= 1) p += __shfl_xor(p, m, 64);  // 8 cgs
      if ((lane & 7) == 0) sP[w4][r0 + i] = p;
    }
  }
  __syncthreads();
  if (tid < MT)
    L[m0 + tid] = sP[0][tid] + sP[1][tid] + sP[2][tid] + sP[3][tid] + ba2[0];
}

// ---------------- Kernel B: softmax-pool ----------------
// one wave per visit, 4 visits/block; 2 codes per iter via float4/lane
__global__ __launch_bounds__(256, 8) void pool_kernel(
    const int* __restrict__ ids, const float* __restrict__ L,
    const float* __restrict__ H2, float* __restrict__ HP) {
  const int wid = threadIdx.x >> 6, lane = threadIdx.x & 63;
  const int v = blockIdx.x * 4 + wid;

  int id = 0;
  float lg = -3.4e38f;
  if (lane < 48) {
    id = ids[(size_t)v * 48 + lane];
    if (id != 0) lg = L[id];   // PAD_IDX==0 masked
  }
  float mx = lg;
#pragma unroll
  for (int m = 32; m; m >>= 1) mx = fmaxf(mx, __shfl_xor(mx, m, 64));
  float e = (lg > -3.0e38f) ? expf(lg - mx) : 0.f;
  float s = e;
#pragma unroll
  for (int m = 32; m; m >>= 1) s += __shfl_xor(s, m, 64);
  const float a = e / s;           // pads: exactly 0

  const int half = lane >> 5, li = lane & 31;
  float4 acc = make_float4(0.f, 0.f, 0.f, 0.f);
#pragma unroll 8
  for (int c = 0; c < 24; ++c) {   // lanes 0-31: even codes, 32-63: odd
    const int cc = 2 * c + half;
    const float ac = __shfl(a, cc, 64);
    const int idc = __shfl(id, cc, 64);
    const float4 h = ((const float4*)(H2 + (size_t)idc * DIM))[li];
    acc.x = fmaf(ac, h.x, acc.x);  // pad: ac==0 exactly -> no-op
    acc.y = fmaf(ac, h.y, acc.y);
    acc.z = fmaf(ac, h.z, acc.z);
    acc.w = fmaf(ac, h.w, acc.w);
  }
  acc.x += __shfl_xor(acc.x, 32, 64);
  acc.y += __shfl_xor(acc.y, 32, 64);
  acc.z += __shfl_xor(acc.z, 32, 64);
  acc.w += __shfl_xor(acc.w, 32, 64);
  if (half == 0) ((float4*)(HP + (size_t)v * DIM))[li] = acc;
}

// ---------------- Kernel C: rho, fused 2 layers (K-split) ----------------
__global__ __launch_bounds__(512, 4) void rho_fused(
    const float* __restrict__ HP, const float* __restrict__ Wr1,
    const float* __restrict__ br1, const float* __restrict__ Wr2,
    const float* __restrict__ br2, float* __restrict__ out) {
  __shared__ float sA[MT][LDP], sB[MT][LDP], sC[MT][LDP];
  const int tid = threadIdx.x;
  const int wid = tid >> 6, lane = tid & 63;
  const int kw = wid >> 2;
  const int w4 = wid & 3;
  const int cg = w4 * 8 + (lane & 7);
  const int c0 = cg * 4;
  const int r0 = (lane >> 3) * 4;
  const int kbase = kw * KH;
  const int m0 = blockIdx.x * MT;

  stage32(HP + (size_t)m0 * DIM, sA, tid);
  __syncthreads();

  float acc[4][4];
  gemm_half(sA, Wr1, cg, r0, kbase, acc);
  if (kw) {
#pragma unroll
    for (int i = 0; i < 4; ++i)
      *(float4*)&sC[r0 + i][c0] =
          make_float4(acc[i][0], acc[i][1], acc[i][2], acc[i][3]);
  }
  __syncthreads();
  if (!kw) {
    float4 bv = ((const float4*)br1)[cg];
#pragma unroll
    for (int i = 0; i < 4; ++i) {
      float4 pc = *(const float4*)&sC[r0 + i][c0];
      float4 o;
      o.x = silu_f(acc[i][0] + pc.x + bv.x);
      o.y = silu_f(acc[i][1] + pc.y + bv.y);
      o.z = silu_f(acc[i][2] + pc.z + bv.z);
      o.w = silu_f(acc[i][3] + pc.w + bv.w);
      *(float4*)&sB[r0 + i][c0] = o;
    }
  }
  __syncthreads();
  gemm_half(sB, Wr2, cg, r0, kbase, acc);
  if (kw) {
#pragma unroll
    for (int i = 0; i < 4; ++i)
      *(float4*)&sC[r0 + i][c0] =
          make_float4(acc[i][0], acc[i][1], acc[i][2], acc[i][3]);
  }
  __syncthreads();
  if (!kw) {
    float4 bv = ((const float4*)br2)[cg];
#pragma unroll
    for (int i = 0; i < 4; ++i) {
      float4 pc = *(const float4*)&sC[r0 + i][c0];
      float4 o;
      o.x = acc[i][0] + pc.x + bv.x;
      o.y = acc[i][1] + pc.y + bv.y;
      o.z = acc[i][2] + pc.z + bv.z;
      o.w = acc[i][3] + pc.w + bv.w;
      *(float4*)&out[(size_t)(m0 + r0 + i) * DIM + c0] = o;
    }
  }
}

extern "C" void kernel_launch(void* const* d_in, const int* in_sizes, int n_in,
                              void* d_out, int out_size, void* d_ws,
                              size_t ws_size, hipStream_t stream) {
  const int*   ids = (const int*)  d_in[0];
  const float* emb = (const float*)d_in[1];
  const float* W1  = (const float*)d_in[2];
  const float* b1  = (const float*)d_in[3];
  const float* W2  = (const float*)d_in[4];
  const float* b2  = (const float*)d_in[5];
  const float* Wa1 = (const float*)d_in[6];
  const float* ba1 = (const float*)d_in[7];
  const float* wa2 = (const float*)d_in[8];
  const float* ba2 = (const float*)d_in[9];
  const float* Wr1 = (const float*)d_in[10];
  const float* br1 = (const float*)d_in[11];
  const float* Wr2 = (const float*)d_in[12];
  const float* br2 = (const float*)d_in[13];
  float* out = (float*)d_out;

  const int VOCAB = 20000, V = 16384;

  float* H2 = (float*)d_ws;                       // 20000*128
  float* L  = H2 + (size_t)VOCAB * DIM;           // 20000
  float* HP = L + VOCAB;                          // 16384*128 (16B-aligned)

  vocab_fused<<<VOCAB / MT, 512, 0, stream>>>(emb, W1, b1, W2, b2, Wa1, ba1,
                                              wa2, ba2, H2, L);
  pool_kernel<<<V / 4, 256, 0, stream>>>(ids, L, H2, HP);
  rho_fused<<<V / MT, 512, 0, stream>>>(HP, Wr1, br1, Wr2, br2, out);
}